// Round 6
// baseline (3171.710 us; speedup 1.0000x reference)
//
#include <hip/hip_runtime.h>
#include <hip/hip_bf16.h>
#include <math.h>

typedef unsigned short u16;
typedef unsigned int u32;
typedef short bf16x8 __attribute__((ext_vector_type(8)));
typedef short s16x4 __attribute__((ext_vector_type(4)));
typedef float f32x4 __attribute__((ext_vector_type(4)));

#define DEV static __device__ __forceinline__

constexpr int D = 768;
constexpr int HH = 12;
constexpr int KD = 64;
constexpr int T = 64;
constexpr int NSEQ = 512;
constexpr int MROWS = NSEQ * T;   // 32768
constexpr int DFF = 3072;
constexpr int PP = 16;

DEV float bfr2f(u16 u){ union{u32 i; float f;} c; c.i = ((u32)u) << 16; return c.f; }
DEV u16 f2bfr(float f){
  union{float f; u32 i;} c; c.f = f;
  u32 r = c.i + 0x7FFFu + ((c.i >> 16) & 1u);   // round-nearest-even
  return (u16)(r >> 16);
}
DEV float lanebc(float x, int l){ return __int_as_float(__builtin_amdgcn_readlane(__float_as_int(x), l)); }
DEV void gld_lds16(const u16* g, u16* l){
  __builtin_amdgcn_global_load_lds((const __attribute__((address_space(1))) void*)g,
                                   (__attribute__((address_space(3))) void*)l, 16, 0, 0);
}

// ---------------- transpose fp32 [R][C] -> bf16 [C][R] (single) ----------------
__global__ __launch_bounds__(256) void k_transpose(const float* __restrict__ W, u16* __restrict__ WT,
                                                   int R, int C){
  __shared__ float tile[32][33];
  int c0 = blockIdx.x * 32, r0 = blockIdx.y * 32;
  int tx = threadIdx.x, ty = threadIdx.y;
  #pragma unroll
  for (int i = 0; i < 32; i += 8)
    tile[ty + i][tx] = W[(size_t)(r0 + ty + i) * C + (c0 + tx)];
  __syncthreads();
  #pragma unroll
  for (int i = 0; i < 32; i += 8)
    WT[(size_t)(c0 + ty + i) * R + (r0 + tx)] = f2bfr(tile[tx][ty + i]);
}

// ---------------- transpose fp32 [R][C] -> split bf16 hi/lo [C][R] ----------------
__global__ __launch_bounds__(256) void k_transpose2(const float* __restrict__ W, u16* __restrict__ WTh,
                                                    u16* __restrict__ WTl, int R, int C){
  __shared__ float tile[32][33];
  int c0 = blockIdx.x * 32, r0 = blockIdx.y * 32;
  int tx = threadIdx.x, ty = threadIdx.y;
  #pragma unroll
  for (int i = 0; i < 32; i += 8)
    tile[ty + i][tx] = W[(size_t)(r0 + ty + i) * C + (c0 + tx)];
  __syncthreads();
  #pragma unroll
  for (int i = 0; i < 32; i += 8){
    float v = tile[tx][ty + i];
    u16 hi = f2bfr(v);
    float rem = v - bfr2f(hi);
    size_t o = (size_t)(c0 + ty + i) * R + (r0 + tx);
    WTh[o] = hi;
    WTl[o] = f2bfr(rem);
  }
}

// ---------------- positional embedding [T][D] ----------------
__global__ void k_pe(float* __restrict__ pe){
  int idx = blockIdx.x * 256 + threadIdx.x;
  if (idx >= T * D) return;
  int t = idx / D, d = idx % D;
  float dv = __expf((float)(d & ~1) * (-9.210340371976184f / (float)D));
  float ang = (float)t * dv;
  pe[idx] = (d & 1) ? cosf(ang) : sinf(ang);
}

// ---------------- patch embedding + LN1 fused: h -> hbuf, LN(h) -> xxf ----------------
__global__ __launch_bounds__(256) void k_patch_ln(const float* __restrict__ x, const float* __restrict__ Wp,
                                                  const float* __restrict__ bp, const float* __restrict__ pe,
                                                  const float* __restrict__ g, const float* __restrict__ b,
                                                  float* __restrict__ h, float* __restrict__ xxf){
  int row = blockIdx.x, t = row & (T - 1);
  int tid = threadIdx.x;
  __shared__ float xs[PP];
  __shared__ float rs[4], rq[4];
  if (tid < PP) xs[tid] = x[(size_t)row * PP + tid];
  __syncthreads();
  float v[3], s = 0.f, sq = 0.f;
  #pragma unroll
  for (int j = 0; j < 3; j++){
    int d = tid + j * 256;
    float acc = bp[d] + pe[t * D + d];
    #pragma unroll
    for (int p = 0; p < PP; p++) acc += xs[p] * Wp[p * D + d];
    v[j] = acc; s += acc; sq += acc * acc;
  }
  #pragma unroll
  for (int o = 32; o; o >>= 1){ s += __shfl_xor(s, o); sq += __shfl_xor(sq, o); }
  if ((tid & 63) == 0){ rs[tid >> 6] = s; rq[tid >> 6] = sq; }
  __syncthreads();
  s = rs[0] + rs[1] + rs[2] + rs[3];
  sq = rq[0] + rq[1] + rq[2] + rq[3];
  float mean = s * (1.f / 768.f);
  float rstd = rsqrtf(sq * (1.f / 768.f) - mean * mean + 1e-5f);
  #pragma unroll
  for (int j = 0; j < 3; j++){
    int d = tid + j * 256;
    h[(size_t)row * D + d] = v[j];
    xxf[(size_t)row * D + d] = (v[j] - mean) * rstd * g[d] + b[d];
  }
}

// ---------------- LN2 + token-shift lerp fused -> bf16 xk ----------------
__global__ __launch_bounds__(256) void k_ln2(const float* __restrict__ X, const float* __restrict__ g,
                                             const float* __restrict__ b, const float* __restrict__ mu,
                                             u16* __restrict__ out){
  int lane = threadIdx.x & 63;
  int row = blockIdx.x * 4 + (threadIdx.x >> 6);
  int t = row & (T - 1);
  const float* xr = X + (size_t)row * D;
  float v[12], s = 0.f, sq = 0.f;
  #pragma unroll
  for (int j = 0; j < 12; j++){ v[j] = xr[lane + j * 64]; s += v[j]; sq += v[j] * v[j]; }
  #pragma unroll
  for (int o = 32; o; o >>= 1){ s += __shfl_xor(s, o); sq += __shfl_xor(sq, o); }
  float mean = s * (1.f / 768.f);
  float rstd = rsqrtf(sq * (1.f / 768.f) - mean * mean + 1e-5f);
  float p[12], meanp = 0.f, rstdp = 0.f;
  if (t){
    const float* xp = xr - D;
    float sp = 0.f, sqp = 0.f;
    #pragma unroll
    for (int j = 0; j < 12; j++){ p[j] = xp[lane + j * 64]; sp += p[j]; sqp += p[j] * p[j]; }
    #pragma unroll
    for (int o = 32; o; o >>= 1){ sp += __shfl_xor(sp, o); sqp += __shfl_xor(sqp, o); }
    meanp = sp * (1.f / 768.f);
    rstdp = rsqrtf(sqp * (1.f / 768.f) - meanp * meanp + 1e-5f);
  }
  u16* orow = out + (size_t)row * D;
  #pragma unroll
  for (int j = 0; j < 12; j++){
    int d = lane + j * 64;
    float cm = (v[j] - mean) * rstd * g[d] + b[d];
    float cp = t ? (p[j] - meanp) * rstdp * g[d] + b[d] : 0.f;
    orow[d] = f2bfr(cm + (cp - cm) * mu[d]);
  }
}

// ---------------- batched split-bf16 mixing GEMM, BM=128 BN=256 ----------------
// A fp32 [M][768] staged once per (m0,k0) with lerp+split (redundancy 3 vs 6).
// B planes pure-copy via global_load_lds. 3-product MFMA per (mi,ni).
// z: 0 r(ACT0) 1 w(ACT1,w0) 2 k(ACT0) 3 v(ACT0) 4 a(ACT2,a0) 5 g(ACT2)
struct MixArgs {
  const u16* bh[6]; const u16* bl[6];
  const float* mu[6]; const float* bias[6];
  float* out[6];
};
__global__ __launch_bounds__(256) void k_gemm_mix(const float* __restrict__ A, MixArgs args, int Kd, int Nc){
  __shared__ __align__(16) u16 Ah[128][40];
  __shared__ __align__(16) u16 Al[128][40];
  __shared__ __align__(16) u16 Bh[256 * 32];
  __shared__ __align__(16) u16 Bl[256 * 32];
  int tid = threadIdx.x;
  int z = blockIdx.z;
  int m0 = blockIdx.x * 128, n0 = blockIdx.y * 256;
  const u16* BTh = args.bh[z];
  const u16* BTl = args.bl[z];
  const float* mu = args.mu[z];
  const float* bias = args.bias[z];
  float* outp = args.out[z];
  int wv = tid >> 6, lane = tid & 63;
  int wrw = (wv >> 1) * 64, wcw = (wv & 1) * 128;
  int lr = lane & 15, kg = (lane >> 4) * 8;
  // B staging map: per plane 4 chunks/thread; chunk = i*256+tid -> row=chunk>>2, slot=chunk&3
  int brow = tid >> 2, bslot = (tid & 3) * 8;
  f32x4 acc[4][8] = {};

  for (int k0 = 0; k0 < Kd; k0 += 32){
    __syncthreads();
    // B: pure copy, 4 chunks per plane per thread (rows brow+64*i)
    #pragma unroll
    for (int i = 0; i < 4; i++){
      int r = brow + i * 64;
      size_t so = (size_t)(n0 + r) * Kd + k0 + bslot;
      int dof = r * 32 + bslot;
      gld_lds16(BTh + so, Bh + dof);
      gld_lds16(BTl + so, Bl + dof);
    }
    // A: fp32 load + token-shift lerp + hi/lo split (once per m-block)
    #pragma unroll
    for (int pass = 0; pass < 4; pass++){
      int c = pass * 256 + tid;
      int rr = c >> 3, c4 = (c & 7) * 4;
      const float* srcA = A + (size_t)(m0 + rr) * Kd + k0 + c4;
      float4 cur = *(const float4*)srcA;
      bool tnz = ((m0 + rr) & (T - 1)) != 0;
      float4 prv = tnz ? *(const float4*)(srcA - Kd) : make_float4(0.f, 0.f, 0.f, 0.f);
      float* cf = (float*)&cur; float* pf = (float*)&prv;
      s16x4 ph, pl;
      #pragma unroll
      for (int j = 0; j < 4; j++){
        float m = mu[k0 + c4 + j];
        float val = cf[j] + (pf[j] - cf[j]) * m;
        u16 hi = f2bfr(val);
        ph[j] = (short)hi;
        pl[j] = (short)f2bfr(val - bfr2f(hi));
      }
      *(s16x4*)&Ah[rr][c4] = ph;
      *(s16x4*)&Al[rr][c4] = pl;
    }
    __syncthreads();
    bf16x8 ah[4], al[4];
    #pragma unroll
    for (int mi = 0; mi < 4; mi++){
      ah[mi] = *(const bf16x8*)&Ah[wrw + mi * 16 + lr][kg];
      al[mi] = *(const bf16x8*)&Al[wrw + mi * 16 + lr][kg];
    }
    #pragma unroll
    for (int ni = 0; ni < 8; ni++){
      int bro = (wcw + ni * 16 + lr) * 32 + kg;
      bf16x8 bh = *(const bf16x8*)&Bh[bro];
      bf16x8 bl = *(const bf16x8*)&Bl[bro];
      #pragma unroll
      for (int mi = 0; mi < 4; mi++){
        acc[mi][ni] = __builtin_amdgcn_mfma_f32_16x16x32_bf16(ah[mi], bh, acc[mi][ni], 0, 0, 0);
        acc[mi][ni] = __builtin_amdgcn_mfma_f32_16x16x32_bf16(al[mi], bh, acc[mi][ni], 0, 0, 0);
        acc[mi][ni] = __builtin_amdgcn_mfma_f32_16x16x32_bf16(ah[mi], bl, acc[mi][ni], 0, 0, 0);
      }
    }
  }

  int actz = (z == 1) ? 1 : (z >= 4 ? 2 : 0);
  int rowb = m0 + wrw + (lane >> 4) * 4;
  int colb = n0 + wcw + lr;
  #pragma unroll
  for (int mi = 0; mi < 4; mi++){
    #pragma unroll
    for (int ni = 0; ni < 8; ni++){
      int gcol = colb + ni * 16;
      float bv = (actz != 0 && bias) ? bias[gcol] : 0.f;
      #pragma unroll
      for (int i = 0; i < 4; i++){
        int grow = rowb + mi * 16 + i;
        float xv = acc[mi][ni][i] + bv;
        size_t o = (size_t)grow * Nc + gcol;
        if (actz == 0)      outp[o] = xv;
        else if (actz == 1) outp[o] = __expf(-__expf(xv));
        else                outp[o] = 1.f / (1.f + __expf(-xv));
      }
    }
  }
}

// ---------------- m97-style single-bf16 GEMM: pure-copy A/B via global_load_lds ----------------
// A bf16 [M][Kd], BT bf16 [Nc][Kd]. ACT: 3 relu^2->bf16 outB, 4 add->fp32 outF
template<int ACT>
__global__ __launch_bounds__(256) void k_gemm97(const u16* __restrict__ A, const u16* __restrict__ BT,
                                                u16* __restrict__ outB, float* __restrict__ outF,
                                                int Kd, int Nc){
  __shared__ __align__(16) u16 As[128 * 32];
  __shared__ __align__(16) u16 Bs[128 * 32];
  int tid = threadIdx.x;
  int m0 = blockIdx.x * 128, n0 = blockIdx.y * 128;
  int wv = tid >> 6, lane = tid & 63;
  int wr = (wv >> 1) * 64, wc = (wv & 1) * 64;
  int lr = lane & 15, kg = (lane >> 4) * 8;
  int r0 = wv * 16 + (lane >> 2);
  int cb = (lane & 3) * 8;
  const u16* sA0 = A + (size_t)(m0 + r0) * Kd + cb;
  const u16* sA1 = A + (size_t)(m0 + r0 + 64) * Kd + cb;
  const u16* sB0 = BT + (size_t)(n0 + r0) * Kd + cb;
  const u16* sB1 = BT + (size_t)(n0 + r0 + 64) * Kd + cb;
  u16* dA0 = As + r0 * 32 + cb;
  u16* dA1 = As + (r0 + 64) * 32 + cb;
  u16* dB0 = Bs + r0 * 32 + cb;
  u16* dB1 = Bs + (r0 + 64) * 32 + cb;
  f32x4 acc[4][4] = {};

  for (int k0 = 0; k0 < Kd; k0 += 32){
    __syncthreads();
    gld_lds16(sA0 + k0, dA0);
    gld_lds16(sA1 + k0, dA1);
    gld_lds16(sB0 + k0, dB0);
    gld_lds16(sB1 + k0, dB1);
    __syncthreads();
    bf16x8 af[4], bfr[4];
    #pragma unroll
    for (int mi = 0; mi < 4; mi++) af[mi] = *(const bf16x8*)&As[(wr + mi * 16 + lr) * 32 + kg];
    #pragma unroll
    for (int ni = 0; ni < 4; ni++) bfr[ni] = *(const bf16x8*)&Bs[(wc + ni * 16 + lr) * 32 + kg];
    #pragma unroll
    for (int mi = 0; mi < 4; mi++){
      #pragma unroll
      for (int ni = 0; ni < 4; ni++){
        acc[mi][ni] = __builtin_amdgcn_mfma_f32_16x16x32_bf16(af[mi], bfr[ni], acc[mi][ni], 0, 0, 0);
      }
    }
  }

  int rowb = m0 + wr + (lane >> 4) * 4;
  int colb = n0 + wc + lr;
  #pragma unroll
  for (int mi = 0; mi < 4; mi++){
    #pragma unroll
    for (int ni = 0; ni < 4; ni++){
      int gcol = colb + ni * 16;
      #pragma unroll
      for (int i = 0; i < 4; i++){
        int grow = rowb + mi * 16 + i;
        float xv = acc[mi][ni][i];
        size_t o = (size_t)grow * Nc + gcol;
        if (ACT == 3){ float rl = fmaxf(xv, 0.f); outB[o] = f2bfr(rl * rl); }
        else outF[o] += xv;
      }
    }
  }
}

// ---------------- RWKV7 recurrence + groupnorm + gate (fp32, readlane broadcasts) ----------------
__global__ __launch_bounds__(64) void k_rwkv(const float* __restrict__ rbuf, const float* __restrict__ wbuf,
                                             const float* __restrict__ kbuf, const float* __restrict__ vbuf,
                                             const float* __restrict__ abuf, const float* __restrict__ gbuf,
                                             const float* __restrict__ gng, const float* __restrict__ gnb,
                                             u16* __restrict__ yg){
  int nh = blockIdx.x;
  int n = nh / HH, hh = nh - n * HH;
  int lane = threadIdx.x;
  float S[64];
  #pragma unroll
  for (int i = 0; i < 64; i++) S[i] = 0.f;
  int dcol = hh * KD + lane;
  float gscale = gng[dcol], gshift = gnb[dcol];
  size_t base = (size_t)n * T * D + dcol;
  for (int t = 0; t < T; t++){
    size_t idx = base + (size_t)t * D;
    float rl = rbuf[idx];
    float wl = wbuf[idx];
    float kl = kbuf[idx];
    float vl = vbuf[idx];
    float al = abuf[idx];
    float gv = gbuf[idx];
    float ss = kl * kl;
    #pragma unroll
    for (int o = 32; o; o >>= 1) ss += __shfl_xor(ss, o);
    float kkl = kl / (sqrtf(ss) + 1e-6f);
    float kal = kkl * al;
    float sa = 0.f;
    #pragma unroll
    for (int j = 0; j < 64; j++){
      S[j] = S[j] * lanebc(wl, j);
      sa += S[j] * lanebc(kkl, j);
    }
    float y = 0.f;
    #pragma unroll
    for (int j = 0; j < 64; j++){
      S[j] += vl * lanebc(kl, j) - sa * lanebc(kal, j);
      y += S[j] * lanebc(rl, j);
    }
    float s1 = y, s2 = y * y;
    #pragma unroll
    for (int o = 32; o; o >>= 1){ s1 += __shfl_xor(s1, o); s2 += __shfl_xor(s2, o); }
    float mean = s1 * (1.f / 64.f);
    float var = s2 * (1.f / 64.f) - mean * mean;
    float yn = (y - mean) * rsqrtf(var + 64e-5f);
    yg[idx] = f2bfr((yn * gscale + gshift) * gv);
  }
}

// ---------------- final projection h @ W_proj + b_proj -> out fp32 ----------------
__global__ __launch_bounds__(256) void k_proj(const float* __restrict__ Hb, const float* __restrict__ Wp,
                                              const float* __restrict__ bp, float* __restrict__ out){
  __shared__ float red[256];
  int row = blockIdx.x, tid = threadIdx.x;
  int p = tid & 15, kg = tid >> 4;
  const float* hr = Hb + (size_t)row * D;
  float acc = 0.f;
  #pragma unroll 8
  for (int i = 0; i < 48; i++){
    int d = kg * 48 + i;
    acc += hr[d] * Wp[d * PP + p];
  }
  red[tid] = acc;
  __syncthreads();
  if (tid < 16){
    float s = 0.f;
    #pragma unroll
    for (int j = 0; j < 16; j++) s += red[j * 16 + tid];
    out[(size_t)row * PP + tid] = s + bp[tid];
  }
}

extern "C" void kernel_launch(void* const* d_in, const int* in_sizes, int n_in,
                              void* d_out, int out_size, void* d_ws, size_t ws_size,
                              hipStream_t stream){
  (void)in_sizes; (void)n_in; (void)out_size;
  const float* x       = (const float*)d_in[0];
  const float* W_patch = (const float*)d_in[1];
  const float* b_patch = (const float*)d_in[2];
  const float* ln1_g   = (const float*)d_in[3];
  const float* ln1_b   = (const float*)d_in[4];
  const float* ln2_g   = (const float*)d_in[5];
  const float* ln2_b   = (const float*)d_in[6];
  const float* mu_r    = (const float*)d_in[7];
  const float* mu_w    = (const float*)d_in[8];
  const float* mu_k    = (const float*)d_in[9];
  const float* mu_v    = (const float*)d_in[10];
  const float* mu_a    = (const float*)d_in[11];
  const float* mu_g    = (const float*)d_in[12];
  const float* mu_c    = (const float*)d_in[13];
  const float* Wr      = (const float*)d_in[14];
  const float* Wk      = (const float*)d_in[15];
  const float* Wv      = (const float*)d_in[16];
  const float* Wg      = (const float*)d_in[17];
  const float* Ww      = (const float*)d_in[18];
  const float* w0      = (const float*)d_in[19];
  const float* Wa      = (const float*)d_in[20];
  const float* a0      = (const float*)d_in[21];
  const float* Wo      = (const float*)d_in[22];
  const float* gn_g    = (const float*)d_in[23];
  const float* gn_b    = (const float*)d_in[24];
  const float* Wc1     = (const float*)d_in[25];
  const float* Wc2     = (const float*)d_in[26];
  const float* W_proj  = (const float*)d_in[27];
  const float* b_proj  = (const float*)d_in[28];
  float* out = (float*)d_out;

  char* ws = (char*)d_ws;
  size_t off = 0;
  auto alloc = [&](size_t bytes) -> char* {
    char* p = ws + off;
    off = (off + bytes + 255) & ~(size_t)255;
    return p;
  };

  // --- static region: split bf16 weights (6 mixing) + single (Wo,Wc1,Wc2) + pe (~24 MB) ---
  const size_t WB = (size_t)D * D * 2;
  u16* WrTh = (u16*)alloc(WB); u16* WrTl = (u16*)alloc(WB);
  u16* WkTh = (u16*)alloc(WB); u16* WkTl = (u16*)alloc(WB);
  u16* WvTh = (u16*)alloc(WB); u16* WvTl = (u16*)alloc(WB);
  u16* WgTh = (u16*)alloc(WB); u16* WgTl = (u16*)alloc(WB);
  u16* WwTh = (u16*)alloc(WB); u16* WwTl = (u16*)alloc(WB);
  u16* WaTh = (u16*)alloc(WB); u16* WaTl = (u16*)alloc(WB);
  u16* WoT  = (u16*)alloc(WB);
  u16* Wc1T = (u16*)alloc((size_t)D * DFF * 2);
  u16* Wc2T = (u16*)alloc((size_t)DFF * D * 2);
  float* pe = (float*)alloc((size_t)T * D * 4);
  size_t wend = off;

  // --- chunking: per chunk 8 fp32 [Mc][768] + ygb bf16 [Mc][768] ---
  int nch = 1;
  size_t Mc = MROWS;
  while (nch < 128){
    size_t need = wend + Mc * (8 * 3072 + 1536) + 64 * 256;
    if (need <= ws_size) break;
    nch *= 2;
    Mc >>= 1;
  }
  float* hbuf = (float*)alloc(Mc * 768 * 4);
  float* xxf  = (float*)alloc(Mc * 768 * 4);
  float* rb   = (float*)alloc(Mc * 768 * 4);
  float* wb   = (float*)alloc(Mc * 768 * 4);
  float* kb   = (float*)alloc(Mc * 768 * 4);
  float* vb   = (float*)alloc(Mc * 768 * 4);
  float* ab   = (float*)alloc(Mc * 768 * 4);
  float* gb   = (float*)alloc(Mc * 768 * 4);
  u16* ygb    = (u16*)alloc(Mc * 768 * 2);
  u16* mid = (u16*)wb;   // spans wb..kb (Mc*3072 bf16 = 2 fp32 buffers)
  u16* xkb = (u16*)xxf;  // xxf dead after mixing GEMMs

  // --- one-time prep ---
  dim3 tb(32, 8);
  k_transpose2<<<dim3(24, 24), tb, 0, stream>>>(Wr, WrTh, WrTl, D, D);
  k_transpose2<<<dim3(24, 24), tb, 0, stream>>>(Wk, WkTh, WkTl, D, D);
  k_transpose2<<<dim3(24, 24), tb, 0, stream>>>(Wv, WvTh, WvTl, D, D);
  k_transpose2<<<dim3(24, 24), tb, 0, stream>>>(Wg, WgTh, WgTl, D, D);
  k_transpose2<<<dim3(24, 24), tb, 0, stream>>>(Ww, WwTh, WwTl, D, D);
  k_transpose2<<<dim3(24, 24), tb, 0, stream>>>(Wa, WaTh, WaTl, D, D);
  k_transpose<<<dim3(24, 24), tb, 0, stream>>>(Wo, WoT, D, D);
  k_transpose<<<dim3(96, 24), tb, 0, stream>>>(Wc1, Wc1T, D, DFF);
  k_transpose<<<dim3(24, 96), tb, 0, stream>>>(Wc2, Wc2T, DFF, D);
  k_pe<<<dim3(192), dim3(256), 0, stream>>>(pe);

  MixArgs margs;
  margs.bh[0] = WrTh; margs.bl[0] = WrTl; margs.mu[0] = mu_r; margs.bias[0] = nullptr; margs.out[0] = rb;
  margs.bh[1] = WwTh; margs.bl[1] = WwTl; margs.mu[1] = mu_w; margs.bias[1] = w0;      margs.out[1] = wb;
  margs.bh[2] = WkTh; margs.bl[2] = WkTl; margs.mu[2] = mu_k; margs.bias[2] = nullptr; margs.out[2] = kb;
  margs.bh[3] = WvTh; margs.bl[3] = WvTl; margs.mu[3] = mu_v; margs.bias[3] = nullptr; margs.out[3] = vb;
  margs.bh[4] = WaTh; margs.bl[4] = WaTl; margs.mu[4] = mu_a; margs.bias[4] = a0;      margs.out[4] = ab;
  margs.bh[5] = WgTh; margs.bl[5] = WgTl; margs.mu[5] = mu_g; margs.bias[5] = nullptr; margs.out[5] = gb;

  // --- per-chunk pipeline (sequence-local everywhere) ---
  for (int c = 0; c < nch; ++c){
    const float* xc = x + (size_t)c * Mc * PP;
    float* outc = out + (size_t)c * Mc * PP;
    int mcb = (int)(Mc / 128);

    k_patch_ln<<<dim3((int)Mc), dim3(256), 0, stream>>>(xc, W_patch, b_patch, pe, ln1_g, ln1_b, hbuf, xxf);

    k_gemm_mix<<<dim3(mcb, 3, 6), 256, 0, stream>>>(xxf, margs, D, D);

    k_rwkv<<<dim3((int)(Mc / T) * HH), dim3(64), 0, stream>>>(rb, wb, kb, vb, ab, gb, gn_g, gn_b, ygb);

    k_gemm97<4><<<dim3(mcb, 6), 256, 0, stream>>>(ygb, WoT, nullptr, hbuf, D, D);

    k_ln2<<<dim3((int)(Mc / 4)), dim3(256), 0, stream>>>(hbuf, ln2_g, ln2_b, mu_c, xkb);
    k_gemm97<3><<<dim3(mcb, DFF / 128), 256, 0, stream>>>(xkb, Wc1T, mid, nullptr, D, DFF);
    k_gemm97<4><<<dim3(mcb, 6), 256, 0, stream>>>(mid, Wc2T, nullptr, hbuf, DFF, D);

    k_proj<<<dim3((int)Mc), dim3(256), 0, stream>>>(hbuf, W_proj, b_proj, outc);
  }
}

// Round 7
// 2355.274 us; speedup vs baseline: 1.3466x; 1.3466x over previous
//
#include <hip/hip_runtime.h>
#include <hip/hip_bf16.h>
#include <math.h>

typedef unsigned short u16;
typedef unsigned int u32;
typedef _Float16 f16x8 __attribute__((ext_vector_type(8)));
typedef float f32x4 __attribute__((ext_vector_type(4)));

#define DEV static __device__ __forceinline__

constexpr int D = 768;
constexpr int HH = 12;
constexpr int KD = 64;
constexpr int T = 64;
constexpr int NSEQ = 512;
constexpr int MROWS = NSEQ * T;   // 32768
constexpr int DFF = 3072;
constexpr int PP = 16;

DEV u16 f2h(float f){ union{_Float16 h; u16 u;} c; c.h = (_Float16)f; return c.u; }
DEV float h2f(u16 u){ union{u16 u; _Float16 h;} c; c.u = u; return (float)c.h; }
DEV float lanebc(float x, int l){ return __int_as_float(__builtin_amdgcn_readlane(__float_as_int(x), l)); }
DEV void gld_lds16(const u16* g, u16* l){
  __builtin_amdgcn_global_load_lds((const __attribute__((address_space(1))) void*)g,
                                   (__attribute__((address_space(3))) void*)l, 16, 0, 0);
}

// ---------------- transpose fp32 [R][C] -> fp16 [C][R] ----------------
__global__ __launch_bounds__(256) void k_transpose(const float* __restrict__ W, u16* __restrict__ WT,
                                                   int R, int C){
  __shared__ float tile[32][33];
  int c0 = blockIdx.x * 32, r0 = blockIdx.y * 32;
  int tx = threadIdx.x, ty = threadIdx.y;
  #pragma unroll
  for (int i = 0; i < 32; i += 8)
    tile[ty + i][tx] = W[(size_t)(r0 + ty + i) * C + (c0 + tx)];
  __syncthreads();
  #pragma unroll
  for (int i = 0; i < 32; i += 8)
    WT[(size_t)(c0 + ty + i) * R + (r0 + tx)] = f2h(tile[tx][ty + i]);
}

// ---------------- positional embedding [T][D] ----------------
__global__ void k_pe(float* __restrict__ pe){
  int idx = blockIdx.x * 256 + threadIdx.x;
  if (idx >= T * D) return;
  int t = idx / D, d = idx % D;
  float dv = __expf((float)(d & ~1) * (-9.210340371976184f / (float)D));
  float ang = (float)t * dv;
  pe[idx] = (d & 1) ? cosf(ang) : sinf(ang);
}

// ---------------- patch embedding + LN1 fused: h -> hbuf, LN(h) -> xxf ----------------
__global__ __launch_bounds__(256) void k_patch_ln(const float* __restrict__ x, const float* __restrict__ Wp,
                                                  const float* __restrict__ bp, const float* __restrict__ pe,
                                                  const float* __restrict__ g, const float* __restrict__ b,
                                                  float* __restrict__ h, float* __restrict__ xxf){
  int row = blockIdx.x, t = row & (T - 1);
  int tid = threadIdx.x;
  __shared__ float xs[PP];
  __shared__ float rs[4], rq[4];
  if (tid < PP) xs[tid] = x[(size_t)row * PP + tid];
  __syncthreads();
  float v[3], s = 0.f, sq = 0.f;
  #pragma unroll
  for (int j = 0; j < 3; j++){
    int d = tid + j * 256;
    float acc = bp[d] + pe[t * D + d];
    #pragma unroll
    for (int p = 0; p < PP; p++) acc += xs[p] * Wp[p * D + d];
    v[j] = acc; s += acc; sq += acc * acc;
  }
  #pragma unroll
  for (int o = 32; o; o >>= 1){ s += __shfl_xor(s, o); sq += __shfl_xor(sq, o); }
  if ((tid & 63) == 0){ rs[tid >> 6] = s; rq[tid >> 6] = sq; }
  __syncthreads();
  s = rs[0] + rs[1] + rs[2] + rs[3];
  sq = rq[0] + rq[1] + rq[2] + rq[3];
  float mean = s * (1.f / 768.f);
  float rstd = rsqrtf(sq * (1.f / 768.f) - mean * mean + 1e-5f);
  #pragma unroll
  for (int j = 0; j < 3; j++){
    int d = tid + j * 256;
    h[(size_t)row * D + d] = v[j];
    xxf[(size_t)row * D + d] = (v[j] - mean) * rstd * g[d] + b[d];
  }
}

// ---------------- lerp-prep: 6 token-shift-lerped fp16 A-planes from xxf ----------------
struct PrepArgs { const float* mu[6]; };
__global__ __launch_bounds__(256) void k_mixprep(const float* __restrict__ X, PrepArgs pa,
                                                 u16* __restrict__ planes, size_t psz){
  int lane = threadIdx.x & 63;
  int row = blockIdx.x * 4 + (threadIdx.x >> 6);
  int t = row & (T - 1);
  const float* xr = X + (size_t)row * D;
  const float* xp = xr - D;
  #pragma unroll
  for (int j = 0; j < 12; j++){
    int d = lane + j * 64;
    float c = xr[d];
    float p = t ? xp[d] : 0.f;
    float dd = p - c;
    #pragma unroll
    for (int z = 0; z < 6; z++)
      planes[z * psz + (size_t)row * D + d] = f2h(c + dd * pa.mu[z][d]);
  }
}

// ---------------- LN2 + token-shift lerp fused -> fp16 xk ----------------
__global__ __launch_bounds__(256) void k_ln2(const float* __restrict__ X, const float* __restrict__ g,
                                             const float* __restrict__ b, const float* __restrict__ mu,
                                             u16* __restrict__ out){
  int lane = threadIdx.x & 63;
  int row = blockIdx.x * 4 + (threadIdx.x >> 6);
  int t = row & (T - 1);
  const float* xr = X + (size_t)row * D;
  float v[12], s = 0.f, sq = 0.f;
  #pragma unroll
  for (int j = 0; j < 12; j++){ v[j] = xr[lane + j * 64]; s += v[j]; sq += v[j] * v[j]; }
  #pragma unroll
  for (int o = 32; o; o >>= 1){ s += __shfl_xor(s, o); sq += __shfl_xor(sq, o); }
  float mean = s * (1.f / 768.f);
  float rstd = rsqrtf(sq * (1.f / 768.f) - mean * mean + 1e-5f);
  float p[12], meanp = 0.f, rstdp = 0.f;
  if (t){
    const float* xp = xr - D;
    float sp = 0.f, sqp = 0.f;
    #pragma unroll
    for (int j = 0; j < 12; j++){ p[j] = xp[lane + j * 64]; sp += p[j]; sqp += p[j] * p[j]; }
    #pragma unroll
    for (int o = 32; o; o >>= 1){ sp += __shfl_xor(sp, o); sqp += __shfl_xor(sqp, o); }
    meanp = sp * (1.f / 768.f);
    rstdp = rsqrtf(sqp * (1.f / 768.f) - meanp * meanp + 1e-5f);
  }
  u16* orow = out + (size_t)row * D;
  #pragma unroll
  for (int j = 0; j < 12; j++){
    int d = lane + j * 64;
    float cm = (v[j] - mean) * rstd * g[d] + b[d];
    float cp = t ? (p[j] - meanp) * rstdp * g[d] + b[d] : 0.f;
    orow[d] = f2h(cm + (cp - cm) * mu[d]);
  }
}

// ---------------- fp16 m97-style GEMM core (pure-copy A/B via global_load_lds) ----------------
// ACT: 0 none->f16, 1 exp(-exp(x+b))->f32, 2 sigmoid(x+b)->f16, 3 relu^2->f16, 4 add->f32
template<int ACT>
__global__ __launch_bounds__(256) void k_g16(const u16* __restrict__ A, const u16* __restrict__ BT,
                                             const float* __restrict__ bias,
                                             u16* __restrict__ outH, float* __restrict__ outF,
                                             int Kd, int Nc){
  __shared__ __align__(16) u16 As[128 * 32];
  __shared__ __align__(16) u16 Bs[128 * 32];
  int tid = threadIdx.x;
  int m0 = blockIdx.x * 128, n0 = blockIdx.y * 128;
  int wv = tid >> 6, lane = tid & 63;
  int wr = (wv >> 1) * 64, wc = (wv & 1) * 64;
  int lr = lane & 15, kg = (lane >> 4) * 8;
  int r0 = wv * 16 + (lane >> 2), cb = (lane & 3) * 8;
  const u16* sA0 = A + (size_t)(m0 + r0) * Kd + cb;
  const u16* sA1 = A + (size_t)(m0 + r0 + 64) * Kd + cb;
  const u16* sB0 = BT + (size_t)(n0 + r0) * Kd + cb;
  const u16* sB1 = BT + (size_t)(n0 + r0 + 64) * Kd + cb;
  u16* dA0 = As + r0 * 32 + cb;
  u16* dA1 = As + (r0 + 64) * 32 + cb;
  u16* dB0 = Bs + r0 * 32 + cb;
  u16* dB1 = Bs + (r0 + 64) * 32 + cb;
  f32x4 acc[4][4] = {};

  for (int k0 = 0; k0 < Kd; k0 += 32){
    __syncthreads();
    gld_lds16(sA0 + k0, dA0);
    gld_lds16(sA1 + k0, dA1);
    gld_lds16(sB0 + k0, dB0);
    gld_lds16(sB1 + k0, dB1);
    __syncthreads();
    f16x8 af[4], bf[4];
    #pragma unroll
    for (int mi = 0; mi < 4; mi++) af[mi] = *(const f16x8*)&As[(wr + mi * 16 + lr) * 32 + kg];
    #pragma unroll
    for (int ni = 0; ni < 4; ni++) bf[ni] = *(const f16x8*)&Bs[(wc + ni * 16 + lr) * 32 + kg];
    #pragma unroll
    for (int mi = 0; mi < 4; mi++){
      #pragma unroll
      for (int ni = 0; ni < 4; ni++){
        acc[mi][ni] = __builtin_amdgcn_mfma_f32_16x16x32_f16(af[mi], bf[ni], acc[mi][ni], 0, 0, 0);
      }
    }
  }

  int rowb = m0 + wr + (lane >> 4) * 4;
  int colb = n0 + wc + lr;
  #pragma unroll
  for (int mi = 0; mi < 4; mi++){
    #pragma unroll
    for (int ni = 0; ni < 4; ni++){
      int gcol = colb + ni * 16;
      float bv = ((ACT == 1 || ACT == 2) && bias) ? bias[gcol] : 0.f;
      #pragma unroll
      for (int i = 0; i < 4; i++){
        int grow = rowb + mi * 16 + i;
        float xv = acc[mi][ni][i] + bv;
        size_t o = (size_t)grow * Nc + gcol;
        if (ACT == 0)      outH[o] = f2h(xv);
        else if (ACT == 1) outF[o] = __expf(-__expf(xv));
        else if (ACT == 2) outH[o] = f2h(1.f / (1.f + __expf(-xv)));
        else if (ACT == 3){ float rl = fmaxf(xv, 0.f); outH[o] = f2h(rl * rl); }
        else               outF[o] += xv;
      }
    }
  }
}

// ---------------- batched mixing GEMM: same core, per-z A-plane / weight / act ----------------
// z: 0 r(f16) 1 w(exp-exp,f32) 2 k(f16) 3 v(f16) 4 a(sig,f16) 5 g(sig,f16)
struct MixArgs {
  const u16* a[6]; const u16* b[6]; const float* bias[6];
  u16* outh[6]; float* outf[6]; int act[6];
};
__global__ __launch_bounds__(256) void k_mix(MixArgs args, int Kd, int Nc){
  __shared__ __align__(16) u16 As[128 * 32];
  __shared__ __align__(16) u16 Bs[128 * 32];
  int tid = threadIdx.x, z = blockIdx.z;
  const u16* A = args.a[z];
  const u16* BT = args.b[z];
  int m0 = blockIdx.x * 128, n0 = blockIdx.y * 128;
  int wv = tid >> 6, lane = tid & 63;
  int wr = (wv >> 1) * 64, wc = (wv & 1) * 64;
  int lr = lane & 15, kg = (lane >> 4) * 8;
  int r0 = wv * 16 + (lane >> 2), cb = (lane & 3) * 8;
  const u16* sA0 = A + (size_t)(m0 + r0) * Kd + cb;
  const u16* sA1 = A + (size_t)(m0 + r0 + 64) * Kd + cb;
  const u16* sB0 = BT + (size_t)(n0 + r0) * Kd + cb;
  const u16* sB1 = BT + (size_t)(n0 + r0 + 64) * Kd + cb;
  u16* dA0 = As + r0 * 32 + cb;
  u16* dA1 = As + (r0 + 64) * 32 + cb;
  u16* dB0 = Bs + r0 * 32 + cb;
  u16* dB1 = Bs + (r0 + 64) * 32 + cb;
  f32x4 acc[4][4] = {};

  for (int k0 = 0; k0 < Kd; k0 += 32){
    __syncthreads();
    gld_lds16(sA0 + k0, dA0);
    gld_lds16(sA1 + k0, dA1);
    gld_lds16(sB0 + k0, dB0);
    gld_lds16(sB1 + k0, dB1);
    __syncthreads();
    f16x8 af[4], bf[4];
    #pragma unroll
    for (int mi = 0; mi < 4; mi++) af[mi] = *(const f16x8*)&As[(wr + mi * 16 + lr) * 32 + kg];
    #pragma unroll
    for (int ni = 0; ni < 4; ni++) bf[ni] = *(const f16x8*)&Bs[(wc + ni * 16 + lr) * 32 + kg];
    #pragma unroll
    for (int mi = 0; mi < 4; mi++){
      #pragma unroll
      for (int ni = 0; ni < 4; ni++){
        acc[mi][ni] = __builtin_amdgcn_mfma_f32_16x16x32_f16(af[mi], bf[ni], acc[mi][ni], 0, 0, 0);
      }
    }
  }

  int act = args.act[z];
  const float* bias = args.bias[z];
  u16* outh = args.outh[z];
  float* outf = args.outf[z];
  int rowb = m0 + wr + (lane >> 4) * 4;
  int colb = n0 + wc + lr;
  #pragma unroll
  for (int mi = 0; mi < 4; mi++){
    #pragma unroll
    for (int ni = 0; ni < 4; ni++){
      int gcol = colb + ni * 16;
      float bv = bias ? bias[gcol] : 0.f;
      #pragma unroll
      for (int i = 0; i < 4; i++){
        int grow = rowb + mi * 16 + i;
        float xv = acc[mi][ni][i] + bv;
        size_t o = (size_t)grow * Nc + gcol;
        if (act == 0)      outh[o] = f2h(xv);
        else if (act == 1) outf[o] = __expf(-__expf(xv));
        else               outh[o] = f2h(1.f / (1.f + __expf(-xv)));
      }
    }
  }
}

// ---------------- RWKV7 recurrence + groupnorm + gate ----------------
// r,k,v,a,g fp16; w fp32. yg may alias rbuf (in-place; r[idx] consumed before write).
__global__ __launch_bounds__(64) void k_rwkv(const u16* rbuf, const float* __restrict__ wbuf,
                                             const u16* __restrict__ kbuf, const u16* __restrict__ vbuf,
                                             const u16* __restrict__ abuf, const u16* __restrict__ gbuf,
                                             const float* __restrict__ gng, const float* __restrict__ gnb,
                                             u16* yg){
  int nh = blockIdx.x;
  int n = nh / HH, hh = nh - n * HH;
  int lane = threadIdx.x;
  float S[64];
  #pragma unroll
  for (int i = 0; i < 64; i++) S[i] = 0.f;
  int dcol = hh * KD + lane;
  float gscale = gng[dcol], gshift = gnb[dcol];
  size_t idx = (size_t)n * T * D + dcol;
  float rl = h2f(rbuf[idx]), wl = wbuf[idx], kl = h2f(kbuf[idx]);
  float vl = h2f(vbuf[idx]), al = h2f(abuf[idx]), gv = h2f(gbuf[idx]);
  for (int t = 0; t < T; t++){
    size_t nidx = idx + D;
    float rn = 0.f, wn = 0.f, kn = 0.f, vn = 0.f, an = 0.f, gn2 = 0.f;
    if (t < T - 1){
      rn = h2f(rbuf[nidx]); wn = wbuf[nidx]; kn = h2f(kbuf[nidx]);
      vn = h2f(vbuf[nidx]); an = h2f(abuf[nidx]); gn2 = h2f(gbuf[nidx]);
    }
    float ss = kl * kl;
    #pragma unroll
    for (int o = 32; o; o >>= 1) ss += __shfl_xor(ss, o);
    float kkl = kl / (sqrtf(ss) + 1e-6f);
    float kal = kkl * al;
    float sa = 0.f;
    #pragma unroll
    for (int j = 0; j < 64; j++){
      S[j] = S[j] * lanebc(wl, j);
      sa += S[j] * lanebc(kkl, j);
    }
    float y = 0.f;
    #pragma unroll
    for (int j = 0; j < 64; j++){
      S[j] += vl * lanebc(kl, j) - sa * lanebc(kal, j);
      y += S[j] * lanebc(rl, j);
    }
    float s1 = y, s2 = y * y;
    #pragma unroll
    for (int o = 32; o; o >>= 1){ s1 += __shfl_xor(s1, o); s2 += __shfl_xor(s2, o); }
    float mean = s1 * (1.f / 64.f);
    float var = s2 * (1.f / 64.f) - mean * mean;
    float yn = (y - mean) * rsqrtf(var + 64e-5f);
    yg[idx] = f2h((yn * gscale + gshift) * gv);
    rl = rn; wl = wn; kl = kn; vl = vn; al = an; gv = gn2;
    idx = nidx;
  }
}

// ---------------- final projection h @ W_proj + b_proj -> out fp32 ----------------
__global__ __launch_bounds__(256) void k_proj(const float* __restrict__ Hb, const float* __restrict__ Wp,
                                              const float* __restrict__ bp, float* __restrict__ out){
  __shared__ float red[256];
  int row = blockIdx.x, tid = threadIdx.x;
  int p = tid & 15, kg = tid >> 4;
  const float* hr = Hb + (size_t)row * D;
  float acc = 0.f;
  #pragma unroll 8
  for (int i = 0; i < 48; i++){
    int d = kg * 48 + i;
    acc += hr[d] * Wp[d * PP + p];
  }
  red[tid] = acc;
  __syncthreads();
  if (tid < 16){
    float s = 0.f;
    #pragma unroll
    for (int j = 0; j < 16; j++) s += red[j * 16 + tid];
    out[(size_t)row * PP + tid] = s + bp[tid];
  }
}

extern "C" void kernel_launch(void* const* d_in, const int* in_sizes, int n_in,
                              void* d_out, int out_size, void* d_ws, size_t ws_size,
                              hipStream_t stream){
  (void)in_sizes; (void)n_in; (void)out_size;
  const float* x       = (const float*)d_in[0];
  const float* W_patch = (const float*)d_in[1];
  const float* b_patch = (const float*)d_in[2];
  const float* ln1_g   = (const float*)d_in[3];
  const float* ln1_b   = (const float*)d_in[4];
  const float* ln2_g   = (const float*)d_in[5];
  const float* ln2_b   = (const float*)d_in[6];
  const float* mu_r    = (const float*)d_in[7];
  const float* mu_w    = (const float*)d_in[8];
  const float* mu_k    = (const float*)d_in[9];
  const float* mu_v    = (const float*)d_in[10];
  const float* mu_a    = (const float*)d_in[11];
  const float* mu_g    = (const float*)d_in[12];
  const float* mu_c    = (const float*)d_in[13];
  const float* Wr      = (const float*)d_in[14];
  const float* Wk      = (const float*)d_in[15];
  const float* Wv      = (const float*)d_in[16];
  const float* Wg      = (const float*)d_in[17];
  const float* Ww      = (const float*)d_in[18];
  const float* w0      = (const float*)d_in[19];
  const float* Wa      = (const float*)d_in[20];
  const float* a0      = (const float*)d_in[21];
  const float* Wo      = (const float*)d_in[22];
  const float* gn_g    = (const float*)d_in[23];
  const float* gn_b    = (const float*)d_in[24];
  const float* Wc1     = (const float*)d_in[25];
  const float* Wc2     = (const float*)d_in[26];
  const float* W_proj  = (const float*)d_in[27];
  const float* b_proj  = (const float*)d_in[28];
  float* out = (float*)d_out;

  char* ws = (char*)d_ws;
  size_t off = 0;
  auto alloc = [&](size_t bytes) -> char* {
    char* p = ws + off;
    off = (off + bytes + 255) & ~(size_t)255;
    return p;
  };

  // --- static region: fp16 transposed weights + pe (~18 MB) ---
  const size_t WB = (size_t)D * D * 2;
  u16* WrT  = (u16*)alloc(WB);
  u16* WwT  = (u16*)alloc(WB);
  u16* WkT  = (u16*)alloc(WB);
  u16* WvT  = (u16*)alloc(WB);
  u16* WaT  = (u16*)alloc(WB);
  u16* WgT  = (u16*)alloc(WB);
  u16* WoT  = (u16*)alloc(WB);
  u16* Wc1T = (u16*)alloc((size_t)D * DFF * 2);
  u16* Wc2T = (u16*)alloc((size_t)DFF * D * 2);
  float* pe = (float*)alloc((size_t)T * D * 4);
  size_t wend = off;

  // --- chunking: per row = hbuf(3072) + xxf(3072) + 6 A-planes(9216) + w f32(3072)
  //     + r,k,v,a,g f16 (7680) = 26112 B; yg in-place into rb; mid aliases A-planes; xk aliases xxf.
  int nch = 1;
  size_t Mc = MROWS;
  while (nch < 128){
    size_t need = wend + Mc * 26112 + 64 * 256;
    if (need <= ws_size) break;
    nch *= 2;
    Mc >>= 1;
  }
  float* hbuf = (float*)alloc(Mc * 768 * 4);
  float* xxf  = (float*)alloc(Mc * 768 * 4);
  u16* ap     = (u16*)alloc(6 * Mc * 768 * 2);   // lerped fp16 planes, z-major
  float* wbf  = (float*)alloc(Mc * 768 * 4);     // w (decay) fp32
  u16* rb     = (u16*)alloc(Mc * 768 * 2);
  u16* kb     = (u16*)alloc(Mc * 768 * 2);
  u16* vb     = (u16*)alloc(Mc * 768 * 2);
  u16* ab     = (u16*)alloc(Mc * 768 * 2);
  u16* gb     = (u16*)alloc(Mc * 768 * 2);
  u16* ygb = rb;            // in-place over r
  u16* mid = ap;            // FFN mid f16 [Mc][3072] = 6144 B/row <= 9216 (A-planes dead)
  u16* xkb = (u16*)xxf;     // xxf dead after prep

  // --- one-time prep ---
  dim3 tb(32, 8);
  k_transpose<<<dim3(24, 24), tb, 0, stream>>>(Wr, WrT, D, D);
  k_transpose<<<dim3(24, 24), tb, 0, stream>>>(Ww, WwT, D, D);
  k_transpose<<<dim3(24, 24), tb, 0, stream>>>(Wk, WkT, D, D);
  k_transpose<<<dim3(24, 24), tb, 0, stream>>>(Wv, WvT, D, D);
  k_transpose<<<dim3(24, 24), tb, 0, stream>>>(Wa, WaT, D, D);
  k_transpose<<<dim3(24, 24), tb, 0, stream>>>(Wg, WgT, D, D);
  k_transpose<<<dim3(24, 24), tb, 0, stream>>>(Wo, WoT, D, D);
  k_transpose<<<dim3(96, 24), tb, 0, stream>>>(Wc1, Wc1T, D, DFF);
  k_transpose<<<dim3(24, 96), tb, 0, stream>>>(Wc2, Wc2T, DFF, D);
  k_pe<<<dim3(192), dim3(256), 0, stream>>>(pe);

  PrepArgs pmu;
  pmu.mu[0] = mu_r; pmu.mu[1] = mu_w; pmu.mu[2] = mu_k;
  pmu.mu[3] = mu_v; pmu.mu[4] = mu_a; pmu.mu[5] = mu_g;

  MixArgs margs;
  const u16* wts[6] = {WrT, WwT, WkT, WvT, WaT, WgT};
  const float* bss[6] = {nullptr, w0, nullptr, nullptr, a0, nullptr};
  u16* oh[6] = {rb, nullptr, kb, vb, ab, gb};
  float* of[6] = {nullptr, wbf, nullptr, nullptr, nullptr, nullptr};
  int acts[6] = {0, 1, 0, 0, 2, 2};
  for (int z = 0; z < 6; z++){
    margs.a[z] = ap + (size_t)z * Mc * 768;
    margs.b[z] = wts[z];
    margs.bias[z] = bss[z];
    margs.outh[z] = oh[z];
    margs.outf[z] = of[z];
    margs.act[z] = acts[z];
  }

  // --- per-chunk pipeline (sequence-local everywhere) ---
  for (int c = 0; c < nch; ++c){
    const float* xc = x + (size_t)c * Mc * PP;
    float* outc = out + (size_t)c * Mc * PP;
    int mcb = (int)(Mc / 128);

    k_patch_ln<<<dim3((int)Mc), dim3(256), 0, stream>>>(xc, W_patch, b_patch, pe, ln1_g, ln1_b, hbuf, xxf);
    k_mixprep<<<dim3((int)(Mc / 4)), dim3(256), 0, stream>>>(xxf, pmu, ap, Mc * 768);

    k_mix<<<dim3(mcb, 6, 6), 256, 0, stream>>>(margs, D, D);

    k_rwkv<<<dim3((int)(Mc / T) * HH), dim3(64), 0, stream>>>(rb, wbf, kb, vb, ab, gb, gn_g, gn_b, ygb);

    k_g16<4><<<dim3(mcb, 6), 256, 0, stream>>>(ygb, WoT, nullptr, nullptr, hbuf, D, D);

    k_ln2<<<dim3((int)(Mc / 4)), dim3(256), 0, stream>>>(hbuf, ln2_g, ln2_b, mu_c, xkb);
    k_g16<3><<<dim3(mcb, DFF / 128), 256, 0, stream>>>(xkb, Wc1T, nullptr, mid, nullptr, D, DFF);
    k_g16<4><<<dim3(mcb, 6), 256, 0, stream>>>(mid, Wc2T, nullptr, nullptr, hbuf, DFF, D);

    k_proj<<<dim3((int)Mc), dim3(256), 0, stream>>>(hbuf, W_proj, b_proj, outc);
  }
}

// Round 8
// 2263.054 us; speedup vs baseline: 1.4015x; 1.0408x over previous
//
#include <hip/hip_runtime.h>
#include <hip/hip_bf16.h>
#include <math.h>

typedef unsigned short u16;
typedef unsigned int u32;
typedef _Float16 f16x8 __attribute__((ext_vector_type(8)));
typedef float f32x4 __attribute__((ext_vector_type(4)));

#define DEV static __device__ __forceinline__

constexpr int D = 768;
constexpr int HH = 12;
constexpr int KD = 64;
constexpr int T = 64;
constexpr int NSEQ = 512;
constexpr int MROWS = NSEQ * T;   // 32768
constexpr int DFF = 3072;
constexpr int PP = 16;

DEV u16 f2h(float f){ union{_Float16 h; u16 u;} c; c.h = (_Float16)f; return c.u; }
DEV float h2f(u16 u){ union{u16 u; _Float16 h;} c; c.u = u; return (float)c.h; }
DEV float lanebc(float x, int l){ return __int_as_float(__builtin_amdgcn_readlane(__float_as_int(x), l)); }
DEV void gld_lds16(const u16* g, u16* l){
  __builtin_amdgcn_global_load_lds((const __attribute__((address_space(1))) void*)g,
                                   (__attribute__((address_space(3))) void*)l, 16, 0, 0);
}

// ---------------- transpose fp32 [R][C] -> fp16 [C][R] ----------------
__global__ __launch_bounds__(256) void k_transpose(const float* __restrict__ W, u16* __restrict__ WT,
                                                   int R, int C){
  __shared__ float tile[32][33];
  int c0 = blockIdx.x * 32, r0 = blockIdx.y * 32;
  int tx = threadIdx.x, ty = threadIdx.y;
  #pragma unroll
  for (int i = 0; i < 32; i += 8)
    tile[ty + i][tx] = W[(size_t)(r0 + ty + i) * C + (c0 + tx)];
  __syncthreads();
  #pragma unroll
  for (int i = 0; i < 32; i += 8)
    WT[(size_t)(c0 + ty + i) * R + (r0 + tx)] = f2h(tile[tx][ty + i]);
}

// ---------------- positional embedding [T][D] ----------------
__global__ void k_pe(float* __restrict__ pe){
  int idx = blockIdx.x * 256 + threadIdx.x;
  if (idx >= T * D) return;
  int t = idx / D, d = idx % D;
  float dv = __expf((float)(d & ~1) * (-9.210340371976184f / (float)D));
  float ang = (float)t * dv;
  pe[idx] = (d & 1) ? cosf(ang) : sinf(ang);
}

// ---------------- patch embedding + LN1 fused: h -> hbuf, LN(h) -> xxf ----------------
__global__ __launch_bounds__(256) void k_patch_ln(const float* __restrict__ x, const float* __restrict__ Wp,
                                                  const float* __restrict__ bp, const float* __restrict__ pe,
                                                  const float* __restrict__ g, const float* __restrict__ b,
                                                  float* __restrict__ h, float* __restrict__ xxf){
  int row = blockIdx.x, t = row & (T - 1);
  int tid = threadIdx.x;
  __shared__ float xs[PP];
  __shared__ float rs[4], rq[4];
  if (tid < PP) xs[tid] = x[(size_t)row * PP + tid];
  __syncthreads();
  float v[3], s = 0.f, sq = 0.f;
  #pragma unroll
  for (int j = 0; j < 3; j++){
    int d = tid + j * 256;
    float acc = bp[d] + pe[t * D + d];
    #pragma unroll
    for (int p = 0; p < PP; p++) acc += xs[p] * Wp[p * D + d];
    v[j] = acc; s += acc; sq += acc * acc;
  }
  #pragma unroll
  for (int o = 32; o; o >>= 1){ s += __shfl_xor(s, o); sq += __shfl_xor(sq, o); }
  if ((tid & 63) == 0){ rs[tid >> 6] = s; rq[tid >> 6] = sq; }
  __syncthreads();
  s = rs[0] + rs[1] + rs[2] + rs[3];
  sq = rq[0] + rq[1] + rq[2] + rq[3];
  float mean = s * (1.f / 768.f);
  float rstd = rsqrtf(sq * (1.f / 768.f) - mean * mean + 1e-5f);
  #pragma unroll
  for (int j = 0; j < 3; j++){
    int d = tid + j * 256;
    h[(size_t)row * D + d] = v[j];
    xxf[(size_t)row * D + d] = (v[j] - mean) * rstd * g[d] + b[d];
  }
}

// ---------------- lerp-prep: 6 token-shift-lerped fp16 A-planes from xxf ----------------
struct PrepArgs { const float* mu[6]; };
__global__ __launch_bounds__(256) void k_mixprep(const float* __restrict__ X, PrepArgs pa,
                                                 u16* __restrict__ planes, size_t psz){
  int lane = threadIdx.x & 63;
  int row = blockIdx.x * 4 + (threadIdx.x >> 6);
  int t = row & (T - 1);
  const float* xr = X + (size_t)row * D;
  const float* xp = xr - D;
  #pragma unroll
  for (int j = 0; j < 12; j++){
    int d = lane + j * 64;
    float c = xr[d];
    float p = t ? xp[d] : 0.f;
    float dd = p - c;
    #pragma unroll
    for (int z = 0; z < 6; z++)
      planes[z * psz + (size_t)row * D + d] = f2h(c + dd * pa.mu[z][d]);
  }
}

// ---------------- LN2 + token-shift lerp fused -> fp16 xk ----------------
__global__ __launch_bounds__(256) void k_ln2(const float* __restrict__ X, const float* __restrict__ g,
                                             const float* __restrict__ b, const float* __restrict__ mu,
                                             u16* __restrict__ out){
  int lane = threadIdx.x & 63;
  int row = blockIdx.x * 4 + (threadIdx.x >> 6);
  int t = row & (T - 1);
  const float* xr = X + (size_t)row * D;
  float v[12], s = 0.f, sq = 0.f;
  #pragma unroll
  for (int j = 0; j < 12; j++){ v[j] = xr[lane + j * 64]; s += v[j]; sq += v[j] * v[j]; }
  #pragma unroll
  for (int o = 32; o; o >>= 1){ s += __shfl_xor(s, o); sq += __shfl_xor(sq, o); }
  float mean = s * (1.f / 768.f);
  float rstd = rsqrtf(sq * (1.f / 768.f) - mean * mean + 1e-5f);
  float p[12], meanp = 0.f, rstdp = 0.f;
  if (t){
    const float* xp = xr - D;
    float sp = 0.f, sqp = 0.f;
    #pragma unroll
    for (int j = 0; j < 12; j++){ p[j] = xp[lane + j * 64]; sp += p[j]; sqp += p[j] * p[j]; }
    #pragma unroll
    for (int o = 32; o; o >>= 1){ sp += __shfl_xor(sp, o); sqp += __shfl_xor(sqp, o); }
    meanp = sp * (1.f / 768.f);
    rstdp = rsqrtf(sqp * (1.f / 768.f) - meanp * meanp + 1e-5f);
  }
  u16* orow = out + (size_t)row * D;
  #pragma unroll
  for (int j = 0; j < 12; j++){
    int d = lane + j * 64;
    float cm = (v[j] - mean) * rstd * g[d] + b[d];
    float cp = t ? (p[j] - meanp) * rstdp * g[d] + b[d] : 0.f;
    orow[d] = f2h(cm + (cp - cm) * mu[d]);
  }
}

// ---------------- fp16 m97-style GEMM core (pure-copy A/B via global_load_lds) ----------------
// ACT: 0 none->f16, 1 exp(-exp(x+b))->f32, 2 sigmoid(x+b)->f16, 3 relu^2->f16, 4 add->f32
template<int ACT>
__global__ __launch_bounds__(256) void k_g16(const u16* __restrict__ A, const u16* __restrict__ BT,
                                             const float* __restrict__ bias,
                                             u16* __restrict__ outH, float* __restrict__ outF,
                                             int Kd, int Nc){
  __shared__ __align__(16) u16 As[128 * 32];
  __shared__ __align__(16) u16 Bs[128 * 32];
  int tid = threadIdx.x;
  int m0 = blockIdx.x * 128, n0 = blockIdx.y * 128;
  int wv = tid >> 6, lane = tid & 63;
  int wr = (wv >> 1) * 64, wc = (wv & 1) * 64;
  int lr = lane & 15, kg = (lane >> 4) * 8;
  int r0 = wv * 16 + (lane >> 2), cb = (lane & 3) * 8;
  const u16* sA0 = A + (size_t)(m0 + r0) * Kd + cb;
  const u16* sA1 = A + (size_t)(m0 + r0 + 64) * Kd + cb;
  const u16* sB0 = BT + (size_t)(n0 + r0) * Kd + cb;
  const u16* sB1 = BT + (size_t)(n0 + r0 + 64) * Kd + cb;
  u16* dA0 = As + r0 * 32 + cb;
  u16* dA1 = As + (r0 + 64) * 32 + cb;
  u16* dB0 = Bs + r0 * 32 + cb;
  u16* dB1 = Bs + (r0 + 64) * 32 + cb;
  f32x4 acc[4][4] = {};

  for (int k0 = 0; k0 < Kd; k0 += 32){
    __syncthreads();
    gld_lds16(sA0 + k0, dA0);
    gld_lds16(sA1 + k0, dA1);
    gld_lds16(sB0 + k0, dB0);
    gld_lds16(sB1 + k0, dB1);
    __syncthreads();
    f16x8 af[4], bf[4];
    #pragma unroll
    for (int mi = 0; mi < 4; mi++) af[mi] = *(const f16x8*)&As[(wr + mi * 16 + lr) * 32 + kg];
    #pragma unroll
    for (int ni = 0; ni < 4; ni++) bf[ni] = *(const f16x8*)&Bs[(wc + ni * 16 + lr) * 32 + kg];
    #pragma unroll
    for (int mi = 0; mi < 4; mi++){
      #pragma unroll
      for (int ni = 0; ni < 4; ni++){
        acc[mi][ni] = __builtin_amdgcn_mfma_f32_16x16x32_f16(af[mi], bf[ni], acc[mi][ni], 0, 0, 0);
      }
    }
  }

  int rowb = m0 + wr + (lane >> 4) * 4;
  int colb = n0 + wc + lr;
  #pragma unroll
  for (int mi = 0; mi < 4; mi++){
    #pragma unroll
    for (int ni = 0; ni < 4; ni++){
      int gcol = colb + ni * 16;
      float bv = ((ACT == 1 || ACT == 2) && bias) ? bias[gcol] : 0.f;
      #pragma unroll
      for (int i = 0; i < 4; i++){
        int grow = rowb + mi * 16 + i;
        float xv = acc[mi][ni][i] + bv;
        size_t o = (size_t)grow * Nc + gcol;
        if (ACT == 0)      outH[o] = f2h(xv);
        else if (ACT == 1) outF[o] = __expf(-__expf(xv));
        else if (ACT == 2) outH[o] = f2h(1.f / (1.f + __expf(-xv)));
        else if (ACT == 3){ float rl = fmaxf(xv, 0.f); outH[o] = f2h(rl * rl); }
        else               outF[o] += xv;
      }
    }
  }
}

// ---------------- batched mixing GEMM: same core, per-z A-plane / weight / act ----------------
// z: 0 r(f16) 1 w(exp-exp,f32) 2 k(f16) 3 v(f16) 4 a(sig,f16) 5 g(sig,f16)
struct MixArgs {
  const u16* a[6]; const u16* b[6]; const float* bias[6];
  u16* outh[6]; float* outf[6]; int act[6];
};
__global__ __launch_bounds__(256) void k_mix(MixArgs args, int Kd, int Nc){
  __shared__ __align__(16) u16 As[128 * 32];
  __shared__ __align__(16) u16 Bs[128 * 32];
  int tid = threadIdx.x, z = blockIdx.z;
  const u16* A = args.a[z];
  const u16* BT = args.b[z];
  int m0 = blockIdx.x * 128, n0 = blockIdx.y * 128;
  int wv = tid >> 6, lane = tid & 63;
  int wr = (wv >> 1) * 64, wc = (wv & 1) * 64;
  int lr = lane & 15, kg = (lane >> 4) * 8;
  int r0 = wv * 16 + (lane >> 2), cb = (lane & 3) * 8;
  const u16* sA0 = A + (size_t)(m0 + r0) * Kd + cb;
  const u16* sA1 = A + (size_t)(m0 + r0 + 64) * Kd + cb;
  const u16* sB0 = BT + (size_t)(n0 + r0) * Kd + cb;
  const u16* sB1 = BT + (size_t)(n0 + r0 + 64) * Kd + cb;
  u16* dA0 = As + r0 * 32 + cb;
  u16* dA1 = As + (r0 + 64) * 32 + cb;
  u16* dB0 = Bs + r0 * 32 + cb;
  u16* dB1 = Bs + (r0 + 64) * 32 + cb;
  f32x4 acc[4][4] = {};

  for (int k0 = 0; k0 < Kd; k0 += 32){
    __syncthreads();
    gld_lds16(sA0 + k0, dA0);
    gld_lds16(sA1 + k0, dA1);
    gld_lds16(sB0 + k0, dB0);
    gld_lds16(sB1 + k0, dB1);
    __syncthreads();
    f16x8 af[4], bf[4];
    #pragma unroll
    for (int mi = 0; mi < 4; mi++) af[mi] = *(const f16x8*)&As[(wr + mi * 16 + lr) * 32 + kg];
    #pragma unroll
    for (int ni = 0; ni < 4; ni++) bf[ni] = *(const f16x8*)&Bs[(wc + ni * 16 + lr) * 32 + kg];
    #pragma unroll
    for (int mi = 0; mi < 4; mi++){
      #pragma unroll
      for (int ni = 0; ni < 4; ni++){
        acc[mi][ni] = __builtin_amdgcn_mfma_f32_16x16x32_f16(af[mi], bf[ni], acc[mi][ni], 0, 0, 0);
      }
    }
  }

  int act = args.act[z];
  const float* bias = args.bias[z];
  u16* outh = args.outh[z];
  float* outf = args.outf[z];
  int rowb = m0 + wr + (lane >> 4) * 4;
  int colb = n0 + wc + lr;
  #pragma unroll
  for (int mi = 0; mi < 4; mi++){
    #pragma unroll
    for (int ni = 0; ni < 4; ni++){
      int gcol = colb + ni * 16;
      float bv = bias ? bias[gcol] : 0.f;
      #pragma unroll
      for (int i = 0; i < 4; i++){
        int grow = rowb + mi * 16 + i;
        float xv = acc[mi][ni][i] + bv;
        size_t o = (size_t)grow * Nc + gcol;
        if (act == 0)      outh[o] = f2h(xv);
        else if (act == 1) outf[o] = __expf(-__expf(xv));
        else               outh[o] = f2h(1.f / (1.f + __expf(-xv)));
      }
    }
  }
}

// ---------------- RWKV7 recurrence + groupnorm + gate (4-wave k-split) ----------------
// One (n,h) per 256-thread block. Wave wv owns state columns [wv*16, wv*16+16).
// lane = v-index. sa/y assembled via LDS partial reduction. yg may alias rbuf.
__global__ __launch_bounds__(256) void k_rwkv(const u16* rbuf, const float* __restrict__ wbuf,
                                              const u16* __restrict__ kbuf, const u16* __restrict__ vbuf,
                                              const u16* __restrict__ abuf, const u16* __restrict__ gbuf,
                                              const float* __restrict__ gng, const float* __restrict__ gnb,
                                              u16* yg){
  __shared__ float sa_red[4][64];
  __shared__ float y_red[4][64];
  int nh = blockIdx.x;
  int n = nh / HH, hh = nh - n * HH;
  int tid = threadIdx.x;
  int wv = __builtin_amdgcn_readfirstlane(tid >> 6);   // SGPR wave id
  int lane = tid & 63;
  float S[16];
  #pragma unroll
  for (int i = 0; i < 16; i++) S[i] = 0.f;
  int dcol = hh * KD + lane;
  float gscale = gng[dcol], gshift = gnb[dcol];
  size_t idx = (size_t)n * T * D + dcol;
  int jbase = wv * 16;
  for (int t = 0; t < T; t++){
    float rl = h2f(rbuf[idx]);
    float wl = wbuf[idx];
    float kl = h2f(kbuf[idx]);
    float vl = h2f(vbuf[idx]);
    float al = h2f(abuf[idx]);
    float ss = kl * kl;
    #pragma unroll
    for (int o = 32; o; o >>= 1) ss += __shfl_xor(ss, o);
    float kkl = kl / (sqrtf(ss) + 1e-6f);
    float kal = kkl * al;
    float sap0 = 0.f, sap1 = 0.f;
    #pragma unroll
    for (int j = 0; j < 16; j += 2){
      S[j]   = S[j]   * lanebc(wl, jbase + j);
      S[j+1] = S[j+1] * lanebc(wl, jbase + j + 1);
      sap0 += S[j]   * lanebc(kkl, jbase + j);
      sap1 += S[j+1] * lanebc(kkl, jbase + j + 1);
    }
    sa_red[wv][lane] = sap0 + sap1;
    __syncthreads();
    float sa = sa_red[0][lane] + sa_red[1][lane] + sa_red[2][lane] + sa_red[3][lane];
    float yp0 = 0.f, yp1 = 0.f;
    #pragma unroll
    for (int j = 0; j < 16; j += 2){
      S[j]   += vl * lanebc(kl, jbase + j)     - sa * lanebc(kal, jbase + j);
      S[j+1] += vl * lanebc(kl, jbase + j + 1) - sa * lanebc(kal, jbase + j + 1);
      yp0 += S[j]   * lanebc(rl, jbase + j);
      yp1 += S[j+1] * lanebc(rl, jbase + j + 1);
    }
    y_red[wv][lane] = yp0 + yp1;
    __syncthreads();
    if (wv == 0){
      float y = y_red[0][lane] + y_red[1][lane] + y_red[2][lane] + y_red[3][lane];
      float s1 = y, s2 = y * y;
      #pragma unroll
      for (int o = 32; o; o >>= 1){ s1 += __shfl_xor(s1, o); s2 += __shfl_xor(s2, o); }
      float mean = s1 * (1.f / 64.f);
      float var = s2 * (1.f / 64.f) - mean * mean;
      float yn = (y - mean) * rsqrtf(var + 64e-5f);
      float gv = h2f(gbuf[idx]);
      yg[idx] = f2h((yn * gscale + gshift) * gv);
    }
    idx += D;
  }
}

// ---------------- final projection h @ W_proj + b_proj -> out fp32 ----------------
__global__ __launch_bounds__(256) void k_proj(const float* __restrict__ Hb, const float* __restrict__ Wp,
                                              const float* __restrict__ bp, float* __restrict__ out){
  __shared__ float red[256];
  int row = blockIdx.x, tid = threadIdx.x;
  int p = tid & 15, kg = tid >> 4;
  const float* hr = Hb + (size_t)row * D;
  float acc = 0.f;
  #pragma unroll 8
  for (int i = 0; i < 48; i++){
    int d = kg * 48 + i;
    acc += hr[d] * Wp[d * PP + p];
  }
  red[tid] = acc;
  __syncthreads();
  if (tid < 16){
    float s = 0.f;
    #pragma unroll
    for (int j = 0; j < 16; j++) s += red[j * 16 + tid];
    out[(size_t)row * PP + tid] = s + bp[tid];
  }
}

extern "C" void kernel_launch(void* const* d_in, const int* in_sizes, int n_in,
                              void* d_out, int out_size, void* d_ws, size_t ws_size,
                              hipStream_t stream){
  (void)in_sizes; (void)n_in; (void)out_size;
  const float* x       = (const float*)d_in[0];
  const float* W_patch = (const float*)d_in[1];
  const float* b_patch = (const float*)d_in[2];
  const float* ln1_g   = (const float*)d_in[3];
  const float* ln1_b   = (const float*)d_in[4];
  const float* ln2_g   = (const float*)d_in[5];
  const float* ln2_b   = (const float*)d_in[6];
  const float* mu_r    = (const float*)d_in[7];
  const float* mu_w    = (const float*)d_in[8];
  const float* mu_k    = (const float*)d_in[9];
  const float* mu_v    = (const float*)d_in[10];
  const float* mu_a    = (const float*)d_in[11];
  const float* mu_g    = (const float*)d_in[12];
  const float* mu_c    = (const float*)d_in[13];
  const float* Wr      = (const float*)d_in[14];
  const float* Wk      = (const float*)d_in[15];
  const float* Wv      = (const float*)d_in[16];
  const float* Wg      = (const float*)d_in[17];
  const float* Ww      = (const float*)d_in[18];
  const float* w0      = (const float*)d_in[19];
  const float* Wa      = (const float*)d_in[20];
  const float* a0      = (const float*)d_in[21];
  const float* Wo      = (const float*)d_in[22];
  const float* gn_g    = (const float*)d_in[23];
  const float* gn_b    = (const float*)d_in[24];
  const float* Wc1     = (const float*)d_in[25];
  const float* Wc2     = (const float*)d_in[26];
  const float* W_proj  = (const float*)d_in[27];
  const float* b_proj  = (const float*)d_in[28];
  float* out = (float*)d_out;

  char* ws = (char*)d_ws;
  size_t off = 0;
  auto alloc = [&](size_t bytes) -> char* {
    char* p = ws + off;
    off = (off + bytes + 255) & ~(size_t)255;
    return p;
  };

  // --- static region: fp16 transposed weights + pe (~18 MB) ---
  const size_t WB = (size_t)D * D * 2;
  u16* WrT  = (u16*)alloc(WB);
  u16* WwT  = (u16*)alloc(WB);
  u16* WkT  = (u16*)alloc(WB);
  u16* WvT  = (u16*)alloc(WB);
  u16* WaT  = (u16*)alloc(WB);
  u16* WgT  = (u16*)alloc(WB);
  u16* WoT  = (u16*)alloc(WB);
  u16* Wc1T = (u16*)alloc((size_t)D * DFF * 2);
  u16* Wc2T = (u16*)alloc((size_t)DFF * D * 2);
  float* pe = (float*)alloc((size_t)T * D * 4);
  size_t wend = off;

  // --- chunking: per row = hbuf(3072) + xxf(3072) + 6 A-planes(9216) + w f32(3072)
  //     + r,k,v,a,g f16 (7680) = 26112 B; yg in-place into rb; mid aliases A-planes; xk aliases xxf.
  int nch = 1;
  size_t Mc = MROWS;
  while (nch < 128){
    size_t need = wend + Mc * 26112 + 64 * 256;
    if (need <= ws_size) break;
    nch *= 2;
    Mc >>= 1;
  }
  float* hbuf = (float*)alloc(Mc * 768 * 4);
  float* xxf  = (float*)alloc(Mc * 768 * 4);
  u16* ap     = (u16*)alloc(6 * Mc * 768 * 2);   // lerped fp16 planes, z-major
  float* wbf  = (float*)alloc(Mc * 768 * 4);     // w (decay) fp32
  u16* rb     = (u16*)alloc(Mc * 768 * 2);
  u16* kb     = (u16*)alloc(Mc * 768 * 2);
  u16* vb     = (u16*)alloc(Mc * 768 * 2);
  u16* ab     = (u16*)alloc(Mc * 768 * 2);
  u16* gb     = (u16*)alloc(Mc * 768 * 2);
  u16* ygb = rb;            // in-place over r
  u16* mid = ap;            // FFN mid f16 [Mc][3072] = 6144 B/row <= 9216 (A-planes dead)
  u16* xkb = (u16*)xxf;     // xxf dead after prep

  // --- one-time prep ---
  dim3 tb(32, 8);
  k_transpose<<<dim3(24, 24), tb, 0, stream>>>(Wr, WrT, D, D);
  k_transpose<<<dim3(24, 24), tb, 0, stream>>>(Ww, WwT, D, D);
  k_transpose<<<dim3(24, 24), tb, 0, stream>>>(Wk, WkT, D, D);
  k_transpose<<<dim3(24, 24), tb, 0, stream>>>(Wv, WvT, D, D);
  k_transpose<<<dim3(24, 24), tb, 0, stream>>>(Wa, WaT, D, D);
  k_transpose<<<dim3(24, 24), tb, 0, stream>>>(Wg, WgT, D, D);
  k_transpose<<<dim3(24, 24), tb, 0, stream>>>(Wo, WoT, D, D);
  k_transpose<<<dim3(96, 24), tb, 0, stream>>>(Wc1, Wc1T, D, DFF);
  k_transpose<<<dim3(24, 96), tb, 0, stream>>>(Wc2, Wc2T, DFF, D);
  k_pe<<<dim3(192), dim3(256), 0, stream>>>(pe);

  PrepArgs pmu;
  pmu.mu[0] = mu_r; pmu.mu[1] = mu_w; pmu.mu[2] = mu_k;
  pmu.mu[3] = mu_v; pmu.mu[4] = mu_a; pmu.mu[5] = mu_g;

  MixArgs margs;
  const u16* wts[6] = {WrT, WwT, WkT, WvT, WaT, WgT};
  const float* bss[6] = {nullptr, w0, nullptr, nullptr, a0, nullptr};
  u16* oh[6] = {rb, nullptr, kb, vb, ab, gb};
  float* of[6] = {nullptr, wbf, nullptr, nullptr, nullptr, nullptr};
  int acts[6] = {0, 1, 0, 0, 2, 2};
  for (int z = 0; z < 6; z++){
    margs.a[z] = ap + (size_t)z * Mc * 768;
    margs.b[z] = wts[z];
    margs.bias[z] = bss[z];
    margs.outh[z] = oh[z];
    margs.outf[z] = of[z];
    margs.act[z] = acts[z];
  }

  // --- per-chunk pipeline (sequence-local everywhere) ---
  for (int c = 0; c < nch; ++c){
    const float* xc = x + (size_t)c * Mc * PP;
    float* outc = out + (size_t)c * Mc * PP;
    int mcb = (int)(Mc / 128);

    k_patch_ln<<<dim3((int)Mc), dim3(256), 0, stream>>>(xc, W_patch, b_patch, pe, ln1_g, ln1_b, hbuf, xxf);
    k_mixprep<<<dim3((int)(Mc / 4)), dim3(256), 0, stream>>>(xxf, pmu, ap, Mc * 768);

    k_mix<<<dim3(mcb, 6, 6), 256, 0, stream>>>(margs, D, D);

    k_rwkv<<<dim3((int)(Mc / T) * HH), dim3(256), 0, stream>>>(rb, wbf, kb, vb, ab, gb, gn_g, gn_b, ygb);

    k_g16<4><<<dim3(mcb, 6), 256, 0, stream>>>(ygb, WoT, nullptr, nullptr, hbuf, D, D);

    k_ln2<<<dim3((int)(Mc / 4)), dim3(256), 0, stream>>>(hbuf, ln2_g, ln2_b, mu_c, xkb);
    k_g16<3><<<dim3(mcb, DFF / 128), 256, 0, stream>>>(xkb, Wc1T, nullptr, mid, nullptr, D, DFF);
    k_g16<4><<<dim3(mcb, 6), 256, 0, stream>>>(mid, Wc2T, nullptr, nullptr, hbuf, DFF, D);

    k_proj<<<dim3((int)Mc), dim3(256), 0, stream>>>(hbuf, W_proj, b_proj, outc);
  }
}